// Round 6
// baseline (212.315 us; speedup 1.0000x reference)
//
#include <hip/hip_runtime.h>
#include <hip/hip_bf16.h>

#define Bb 4
#define Ss 512
#define Hh 768
#define Dd 24
#define Mm 96
#define Oo 768

typedef __bf16 bf16x8 __attribute__((ext_vector_type(8)));
typedef float f32x4 __attribute__((ext_vector_type(4)));

// ---------------------------------------------------------------------------
// Kernel A: Zj = H_j @ Wpj (packed [row][24]), Zi = H_i @ Wpi (padded [row][32],
// slot 24 = 1.0 bias column, 25..31 = 0 -> MFMA-ready B operand rows)
// ---------------------------------------------------------------------------
__global__ __launch_bounds__(256) void proj_kernel(
    const float* __restrict__ Hj, const float* __restrict__ Hi,
    const float* __restrict__ Wpj, const float* __restrict__ Wpi,
    float* __restrict__ Zj, float* __restrict__ Zip)
{
    const int row = blockIdx.x;
    const int which = blockIdx.y;
    const float* src = (which ? Hi : Hj) + (size_t)row * Hh;
    const float* W = which ? Wpi : Wpj;
    __shared__ float rowbuf[Hh];
    __shared__ float partial[8][Dd];
    const int tid = threadIdx.x;
    for (int i = tid; i < Hh; i += 256) rowbuf[i] = src[i];
    __syncthreads();
    if (tid < 192) {
        const int d = tid % Dd;
        const int c = tid / Dd;
        const int h0 = c * 96;
        float s = 0.f;
        #pragma unroll 4
        for (int h = h0; h < h0 + 96; ++h) s = fmaf(rowbuf[h], W[h * Dd + d], s);
        partial[c][d] = s;
    }
    __syncthreads();
    if (tid < Dd) {
        float s = 0.f;
        #pragma unroll
        for (int c = 0; c < 8; ++c) s += partial[c][tid];
        if (which) Zip[(size_t)row * 32 + tid] = s;
        else       Zj[(size_t)row * Dd + tid] = s;
    }
    if (which && tid >= Dd && tid < 32)
        Zip[(size_t)row * 32 + tid] = (tid == 24) ? 1.0f : 0.0f;
}

// ---------------------------------------------------------------------------
// WsT[m][x] = Ws1[x][m]  (96x96 fp32 transpose; x: 0:24=W1j 24:48=W1i
// 48:72=W1h 72:96=W1d). Single block.
// ---------------------------------------------------------------------------
__global__ __launch_bounds__(256) void wst_kernel(
    const float* __restrict__ Ws1, float* __restrict__ WsT)
{
    __shared__ float W[96][97];
    for (int i = threadIdx.x; i < 96 * 96; i += 256) W[i / 96][i % 96] = Ws1[i];
    __syncthreads();
    for (int i = threadIdx.x; i < 96 * 96; i += 256) WsT[i] = W[i % 96][i / 96];
}

// ---------------------------------------------------------------------------
// tj_all[p][m] = bs1[m] + sum_d Zj[p,d] * W1j[d][m]   (coalesced over m)
// ---------------------------------------------------------------------------
__global__ __launch_bounds__(256) void tj_kernel(
    const float* __restrict__ Zj, const float* __restrict__ Ws1,
    const float* __restrict__ bs1, float* __restrict__ tj_all)
{
    const int idx = blockIdx.x * 256 + threadIdx.x;   // 2048*96
    const int p = idx / 96, m = idx % 96;
    float s = bs1[m];
    const float* zr = Zj + (size_t)p * Dd;
    #pragma unroll
    for (int d = 0; d < Dd; ++d) s = fmaf(zr[d], Ws1[d * Mm + m], s);
    tj_all[idx] = s;
}

// ---------------------------------------------------------------------------
// Hj fp32 -> bf16 into segment 1 of concatenated A  ([2048][2304])
// ---------------------------------------------------------------------------
__global__ __launch_bounds__(256) void hjconv_kernel(
    const float* __restrict__ Hjf, __bf16* __restrict__ Ac)
{
    const int idx = blockIdx.x * 256 + threadIdx.x;
    const int row = idx / 96, c8 = idx % 96;
    const float* s = Hjf + (size_t)row * Hh + c8 * 8;
    const float4 u = *(const float4*)s;
    const float4 v = *(const float4*)(s + 4);
    bf16x8 o;
    o[0]=(__bf16)u.x; o[1]=(__bf16)u.y; o[2]=(__bf16)u.z; o[3]=(__bf16)u.w;
    o[4]=(__bf16)v.x; o[5]=(__bf16)v.y; o[6]=(__bf16)v.z; o[7]=(__bf16)v.w;
    *(bf16x8*)&Ac[(size_t)row * 2304 + Hh + c8 * 8] = o;
}

// ---------------------------------------------------------------------------
// Transpose + fp32->bf16:  dst[c][r] = bf16(src[r][c]),  tiles 32x32
// ---------------------------------------------------------------------------
__global__ __launch_bounds__(256) void transpose_bf16_kernel(
    const float* __restrict__ src, __bf16* __restrict__ dst,
    int R, int C, long sbatch, long dbatch)
{
    const float* s = src + (size_t)blockIdx.z * sbatch;
    __bf16* d = dst + (size_t)blockIdx.z * dbatch;
    __shared__ float t[32][33];
    const int x = threadIdx.x & 31, y = threadIdx.x >> 5;
    const int c0 = blockIdx.x * 32, r0 = blockIdx.y * 32;
    #pragma unroll
    for (int i = 0; i < 4; ++i)
        t[y + 8 * i][x] = s[(size_t)(r0 + y + 8 * i) * C + c0 + x];
    __syncthreads();
    #pragma unroll
    for (int i = 0; i < 4; ++i)
        d[(size_t)(c0 + y + 8 * i) * R + r0 + x] = (__bf16)t[x][y + 8 * i];
}

// ---------------------------------------------------------------------------
// Kernel B (MFMA): per (b,p) block: logits over all 512 q + softmax -> bf16.
// A = weights (m on C-rows) built per block from WsT + tj_all (contiguous
// loads); B = Zi_pad fragments: one fully-coalesced 2KB wave load per tile,
// prefetched one t ahead. m-reduction in-lane + 2 shfl.
// ---------------------------------------------------------------------------
__global__ __launch_bounds__(256) void pair_kernel(
    const float* __restrict__ Zj, const float* __restrict__ Zip,
    const float* __restrict__ WsT, const float* __restrict__ tj_all,
    const float* __restrict__ ws2, const float* __restrict__ bs2p,
    const int* __restrict__ mask, __bf16* __restrict__ probs)
{
    const int bp = blockIdx.x;
    const int b  = bp >> 9;              // S = 512
    const int tid  = threadIdx.x;
    const int lane = tid & 63;
    const int wid  = tid >> 6;
    const int col  = lane & 15;          // A: m-row / B: q-col
    const int g    = lane >> 4;          // k-quad

    __shared__ float logitsl[Ss];
    __shared__ float red[8];

    const float km = (g < 3) ? 1.0f : 0.0f;
    float zj8[8];
    if (g < 3) {
        const float* zr = Zj + (size_t)bp * Dd + g * 8;
        const float4 u = *(const float4*)zr;
        const float4 v = *(const float4*)(zr + 4);
        zj8[0]=u.x; zj8[1]=u.y; zj8[2]=u.z; zj8[3]=u.w;
        zj8[4]=v.x; zj8[5]=v.y; zj8[6]=v.z; zj8[7]=v.w;
    } else {
        #pragma unroll
        for (int j = 0; j < 8; ++j) zj8[j] = 0.f;
    }

    // A-fragments: aw[n][0] k 0..31 (wcomb | bias col), aw[n][1] k 32..63 (W1d)
    bf16x8 aw[6][2];
    float ws2r[6][4];
    #pragma unroll
    for (int n = 0; n < 6; ++n) {
        const int m = n * 16 + col;
        const float4 w4 = *(const float4*)&ws2[n * 16 + g * 4];
        ws2r[n][0] = w4.x; ws2r[n][1] = w4.y; ws2r[n][2] = w4.z; ws2r[n][3] = w4.w;
        bf16x8 a0, a1;
        if (g < 3) {
            const float* wr = WsT + (size_t)m * 96;
            const float4 i0 = *(const float4*)(wr + 24 + g * 8);
            const float4 i1 = *(const float4*)(wr + 28 + g * 8);
            const float4 h0 = *(const float4*)(wr + 48 + g * 8);
            const float4 h1 = *(const float4*)(wr + 52 + g * 8);
            const float4 d0 = *(const float4*)(wr + 72 + g * 8);
            const float4 d1 = *(const float4*)(wr + 76 + g * 8);
            a0[0]=(__bf16)fmaf(zj8[0], h0.x, i0.x); a0[1]=(__bf16)fmaf(zj8[1], h0.y, i0.y);
            a0[2]=(__bf16)fmaf(zj8[2], h0.z, i0.z); a0[3]=(__bf16)fmaf(zj8[3], h0.w, i0.w);
            a0[4]=(__bf16)fmaf(zj8[4], h1.x, i1.x); a0[5]=(__bf16)fmaf(zj8[5], h1.y, i1.y);
            a0[6]=(__bf16)fmaf(zj8[6], h1.z, i1.z); a0[7]=(__bf16)fmaf(zj8[7], h1.w, i1.w);
            a1[0]=(__bf16)d0.x; a1[1]=(__bf16)d0.y; a1[2]=(__bf16)d0.z; a1[3]=(__bf16)d0.w;
            a1[4]=(__bf16)d1.x; a1[5]=(__bf16)d1.y; a1[6]=(__bf16)d1.z; a1[7]=(__bf16)d1.w;
        } else {
            #pragma unroll
            for (int j = 0; j < 8; ++j) { a0[j] = (__bf16)0.f; a1[j] = (__bf16)0.f; }
            a0[0] = (__bf16)tj_all[(size_t)bp * 96 + m];   // k=24 bias row
        }
        aw[n][0] = a0; aw[n][1] = a1;
    }

    // B fragments from Zi_pad [row][32]; wave load = 64 lanes x 32B contiguous
    const float* zb = Zip + ((size_t)(b * Ss + wid * 128 + col) * 32) + g * 8;

    float4 cu, cv;
    cu = *(const float4*)zb; cv = *(const float4*)(zb + 4);

    for (int t = 0; t < 8; ++t) {
        const float4 u = cu, v = cv;
        if (t + 1 < 8) {
            const float* zr = zb + (size_t)(t + 1) * 16 * 32;
            cu = *(const float4*)zr; cv = *(const float4*)(zr + 4);
        }
        bf16x8 b0, b1;
        b0[0]=(__bf16)u.x; b0[1]=(__bf16)u.y; b0[2]=(__bf16)u.z; b0[3]=(__bf16)u.w;
        b0[4]=(__bf16)v.x; b0[5]=(__bf16)v.y; b0[6]=(__bf16)v.z; b0[7]=(__bf16)v.w;
        b1[0]=(__bf16)(fabsf(zj8[0]-u.x)*km); b1[1]=(__bf16)(fabsf(zj8[1]-u.y)*km);
        b1[2]=(__bf16)(fabsf(zj8[2]-u.z)*km); b1[3]=(__bf16)(fabsf(zj8[3]-u.w)*km);
        b1[4]=(__bf16)(fabsf(zj8[4]-v.x)*km); b1[5]=(__bf16)(fabsf(zj8[5]-v.y)*km);
        b1[6]=(__bf16)(fabsf(zj8[6]-v.z)*km); b1[7]=(__bf16)(fabsf(zj8[7]-v.w)*km);

        f32x4 acc[6];
        #pragma unroll
        for (int n = 0; n < 6; ++n) acc[n] = (f32x4){0.f, 0.f, 0.f, 0.f};
        #pragma unroll
        for (int n = 0; n < 6; ++n) {
            acc[n] = __builtin_amdgcn_mfma_f32_16x16x32_bf16(aw[n][0], b0, acc[n], 0, 0, 0);
            acc[n] = __builtin_amdgcn_mfma_f32_16x16x32_bf16(aw[n][1], b1, acc[n], 0, 0, 0);
        }

        float lsum = 0.f;
        #pragma unroll
        for (int n = 0; n < 6; ++n)
            #pragma unroll
            for (int r = 0; r < 4; ++r)
                lsum = fmaf(fmaxf(acc[n][r], 0.f), ws2r[n][r], lsum);
        lsum += __shfl_xor(lsum, 16);
        lsum += __shfl_xor(lsum, 32);
        if (lane < 16) logitsl[wid * 128 + t * 16 + lane] = lsum;
    }
    __syncthreads();

    // mask + bias + softmax over 512 q (2 per thread)
    const float bs2v = bs2p[0];
    const int* mrow = mask + (size_t)b * Ss;
    float l0 = logitsl[tid]       + bs2v + (1.0f - (float)mrow[tid])       * (-3.402823466e+38f);
    float l1 = logitsl[tid + 256] + bs2v + (1.0f - (float)mrow[tid + 256]) * (-3.402823466e+38f);
    float vmax = fmaxf(l0, l1);
    #pragma unroll
    for (int off = 32; off > 0; off >>= 1) vmax = fmaxf(vmax, __shfl_xor(vmax, off));
    if (lane == 0) red[wid] = vmax;
    __syncthreads();
    const float mx = fmaxf(fmaxf(red[0], red[1]), fmaxf(red[2], red[3]));
    const float e0 = __expf(l0 - mx);
    const float e1 = __expf(l1 - mx);
    float vs = e0 + e1;
    #pragma unroll
    for (int off = 32; off > 0; off >>= 1) vs += __shfl_xor(vs, off);
    if (lane == 0) red[4 + wid] = vs;
    __syncthreads();
    const float inv = 1.0f / (red[4] + red[5] + red[6] + red[7]);
    __bf16* prow = probs + (size_t)bp * Ss;
    prow[tid] = (__bf16)(e0 * inv);
    prow[tid + 256] = (__bf16)(e1 * inv);
}

// ---------------------------------------------------------------------------
// bf16 MFMA GEMM, 64x64 block tile, BK=64, LDS single-buffer (padded) with
// register prefetch of the next K-slab. 4 waves (2x2), wave tile 32x32.
// MODE 0: ctx = probs@HiT(batch)  -> write A_concat seg0 (ctx) & seg2 (ctx*Hj)
// MODE 1: mhid = relu(Acat@Wv1T + bv1) -> bf16
// MODE 2: out  = alpha*(mhid@Wv2T + bv2) -> fp32
// ---------------------------------------------------------------------------
template<int MODE>
__global__ __launch_bounds__(256) void gemm_kernel(
    const __bf16* __restrict__ A, const __bf16* __restrict__ Bt,
    const float* __restrict__ Hjf, const float* __restrict__ bias,
    const float* __restrict__ alphap,
    __bf16* __restrict__ obf, float* __restrict__ of)
{
    constexpr int K = (MODE == 0) ? 512 : (MODE == 1) ? 2304 : 768;
    constexpr int NIT = K / 64;
    constexpr int LDT = 72;

    __shared__ __bf16 As[64 * LDT];
    __shared__ __bf16 Bs[64 * LDT];

    const int tid = threadIdx.x;
    const int lane = tid & 63;
    const int wid = tid >> 6;
    const int col = lane & 15, g = lane >> 4;
    const int wm = wid >> 1, wn = wid & 1;
    const int r0 = blockIdx.x * 64;
    const int n0 = blockIdx.y * 64;
    const __bf16* Btb = (MODE == 0) ? Bt + (size_t)(r0 >> 9) * (Hh * Ss) : Bt;

    const int srow = tid >> 2;
    const int sc8  = (tid & 3) * 16;
    const __bf16* ag = A   + (size_t)(r0 + srow) * K + sc8;
    const __bf16* bg = Btb + (size_t)(n0 + srow) * K + sc8;
    __bf16* asl = &As[srow * LDT + sc8];
    __bf16* bsl = &Bs[srow * LDT + sc8];

    bf16x8 ra0 = *(const bf16x8*)(ag);
    bf16x8 ra1 = *(const bf16x8*)(ag + 8);
    bf16x8 rb0 = *(const bf16x8*)(bg);
    bf16x8 rb1 = *(const bf16x8*)(bg + 8);

    f32x4 acc[2][2];
    #pragma unroll
    for (int mi = 0; mi < 2; ++mi)
        #pragma unroll
        for (int ni = 0; ni < 2; ++ni) acc[mi][ni] = (f32x4){0.f, 0.f, 0.f, 0.f};

    for (int it = 0; it < NIT; ++it) {
        __syncthreads();
        *(bf16x8*)(asl)     = ra0;
        *(bf16x8*)(asl + 8) = ra1;
        *(bf16x8*)(bsl)     = rb0;
        *(bf16x8*)(bsl + 8) = rb1;
        __syncthreads();
        if (it + 1 < NIT) {
            const int kk = (it + 1) * 64;
            ra0 = *(const bf16x8*)(ag + kk);
            ra1 = *(const bf16x8*)(ag + kk + 8);
            rb0 = *(const bf16x8*)(bg + kk);
            rb1 = *(const bf16x8*)(bg + kk + 8);
        }
        #pragma unroll
        for (int h = 0; h < 2; ++h) {
            bf16x8 a0 = *(const bf16x8*)&As[(wm * 32 + col)      * LDT + h * 32 + g * 8];
            bf16x8 a1 = *(const bf16x8*)&As[(wm * 32 + 16 + col) * LDT + h * 32 + g * 8];
            bf16x8 b0 = *(const bf16x8*)&Bs[(wn * 32 + col)      * LDT + h * 32 + g * 8];
            bf16x8 b1 = *(const bf16x8*)&Bs[(wn * 32 + 16 + col) * LDT + h * 32 + g * 8];
            acc[0][0] = __builtin_amdgcn_mfma_f32_16x16x32_bf16(a0, b0, acc[0][0], 0, 0, 0);
            acc[0][1] = __builtin_amdgcn_mfma_f32_16x16x32_bf16(a0, b1, acc[0][1], 0, 0, 0);
            acc[1][0] = __builtin_amdgcn_mfma_f32_16x16x32_bf16(a1, b0, acc[1][0], 0, 0, 0);
            acc[1][1] = __builtin_amdgcn_mfma_f32_16x16x32_bf16(a1, b1, acc[1][1], 0, 0, 0);
        }
    }

    const float al = (MODE == 2) ? alphap[0] : 0.f;
    #pragma unroll
    for (int mi = 0; mi < 2; ++mi) {
        #pragma unroll
        for (int r = 0; r < 4; ++r) {
            const int row = r0 + wm * 32 + mi * 16 + g * 4 + r;
            #pragma unroll
            for (int ni = 0; ni < 2; ++ni) {
                const int cn = n0 + wn * 32 + ni * 16 + col;
                const float v = acc[mi][ni][r];
                if (MODE == 0) {
                    const float hjv = Hjf[(size_t)row * Hh + cn];
                    obf[(size_t)row * 2304 + cn] = (__bf16)v;
                    obf[(size_t)row * 2304 + 1536 + cn] = (__bf16)(v * hjv);
                } else if (MODE == 1) {
                    obf[(size_t)row * Oo + cn] = (__bf16)fmaxf(v + bias[cn], 0.f);
                } else {
                    of[(size_t)row * Hh + cn] = al * (v + bias[cn]);
                }
            }
        }
    }
}

// ---------------------------------------------------------------------------
extern "C" void kernel_launch(void* const* d_in, const int* in_sizes, int n_in,
                              void* d_out, int out_size, void* d_ws, size_t ws_size,
                              hipStream_t stream)
{
    const float* Hj  = (const float*)d_in[0];
    const float* Hi  = (const float*)d_in[1];
    const float* Wpj = (const float*)d_in[2];
    const float* Wpi = (const float*)d_in[3];
    const float* Ws1 = (const float*)d_in[4];
    const float* bs1 = (const float*)d_in[5];
    const float* ws2 = (const float*)d_in[6];
    const float* bs2 = (const float*)d_in[7];
    const float* Wv1 = (const float*)d_in[8];
    const float* bv1 = (const float*)d_in[9];
    const float* Wv2 = (const float*)d_in[10];
    const float* bv2 = (const float*)d_in[11];
    const float* alpha = (const float*)d_in[12];
    const int* mask  = (const int*)d_in[13];

    float* ws = (float*)d_ws;
    float* Zj     = ws;                                  // 49152
    float* Zip    = Zj + 49152;                          // 65536 (2048x32 padded)
    float* WsT    = Zip + 65536;                         // 9216
    float* tj_all = WsT + 9216;                          // 196608
    float* R0f    = tj_all + 196608;                     // 524288
    float* R1f    = R0f + 524288;                        // 786432
    float* Acat_f = R1f + 786432;                        // 2359296
    float* Wv1T_f = Acat_f + 2359296;                    // 884736
    // total ~19.5 MB

    __bf16* probs_bf = (__bf16*)R0f;                     // [2048][512]
    __bf16* Wv2T     = (__bf16*)R0f;                     // [768][768] (after gemm0)
    __bf16* HiT      = (__bf16*)R1f;                     // [4][768][512]
    __bf16* mhid_bf  = (__bf16*)R1f;                     // [2048][768] (after gemm0)
    __bf16* Acat     = (__bf16*)Acat_f;                  // [2048][2304]
    __bf16* Wv1T     = (__bf16*)Wv1T_f;                  // [768][2304]

    proj_kernel<<<dim3(Bb * Ss, 2), 256, 0, stream>>>(Hj, Hi, Wpj, Wpi, Zj, Zip);
    wst_kernel<<<dim3(1), 256, 0, stream>>>(Ws1, WsT);
    tj_kernel<<<dim3(768), 256, 0, stream>>>(Zj, Ws1, bs1, tj_all);
    transpose_bf16_kernel<<<dim3(Hh / 32, Ss / 32, Bb), 256, 0, stream>>>(
        Hi, HiT, Ss, Hh, (long)Ss * Hh, (long)Hh * Ss);
    transpose_bf16_kernel<<<dim3(Oo / 32, 3 * Hh / 32, 1), 256, 0, stream>>>(
        Wv1, Wv1T, 3 * Hh, Oo, 0, 0);
    hjconv_kernel<<<dim3(768), 256, 0, stream>>>(Hj, Acat);
    pair_kernel<<<dim3(Bb * Ss), 256, 0, stream>>>(
        Zj, Zip, WsT, tj_all, ws2, bs2, mask, probs_bf);
    gemm_kernel<0><<<dim3(2048 / 64, Hh / 64), 256, 0, stream>>>(
        probs_bf, HiT, Hj, nullptr, nullptr, Acat, nullptr);
    transpose_bf16_kernel<<<dim3(Hh / 32, Oo / 32, 1), 256, 0, stream>>>(
        Wv2, Wv2T, Oo, Hh, 0, 0);
    gemm_kernel<1><<<dim3(2048 / 64, Oo / 64), 256, 0, stream>>>(
        Acat, Wv1T, nullptr, bv1, nullptr, mhid_bf, nullptr);
    gemm_kernel<2><<<dim3(2048 / 64, Hh / 64), 256, 0, stream>>>(
        mhid_bf, Wv2T, nullptr, bv2, alpha, nullptr, (float*)d_out);
}